// Round 7
// baseline (71.133 us; speedup 1.0000x reference)
//
#include <hip/hip_runtime.h>

#define NEG_SLOPE 0.2f

// ws layout (in floats)
#define OFF_U   0        // 3 layers * 256 (u_src[128] | u_dst[128])
#define OFF_WT  1024     // 3 * 16384 (W transposed: WT[d*128+e] = W[e*128+d])
#define OFF_XT  50176    // x~ partials: [b][p][h][d] = 64*16*2*128 floats

__device__ __forceinline__ float lrelu(float z) { return z >= 0.f ? z : NEG_SLOPE * z; }

__device__ __forceinline__ unsigned short f2bf(float f) {   // RTNE float->bf16
  unsigned u = __float_as_uint(f);
  u += 0x7FFFu + ((u >> 16) & 1u);
  return (unsigned short)(u >> 16);
}

// ---------------------------------------------------------------------------
// Setup: grid 48 = 3 layers x 16 sub-blocks. LDS-tiled coalesced transpose;
// sub==0 block also computes u vectors (u = a @ W).  [verbatim from round 6]
__global__ __launch_bounds__(256) void setup_kernel(
    const float* __restrict__ W0, const float* __restrict__ as0, const float* __restrict__ ad0,
    const float* __restrict__ W1, const float* __restrict__ as1, const float* __restrict__ ad1,
    const float* __restrict__ W2, const float* __restrict__ as2, const float* __restrict__ ad2,
    float* __restrict__ ws) {
  __shared__ float tile[8][132];
  const int bid = blockIdx.x;
  const int l = bid >> 4, sub = bid & 15;
  const int tid = threadIdx.x;
  const float* W = (l == 0) ? W0 : (l == 1) ? W1 : W2;
  float* WT = ws + OFF_WT + l * 16384;
  const int e0 = sub * 8;

#pragma unroll
  for (int i = 0; i < 4; ++i) {     // read 8 rows of W, coalesced
    const int idx = i * 256 + tid;
    tile[idx >> 7][idx & 127] = W[(e0 + (idx >> 7)) * 128 + (idx & 127)];
  }
  __syncthreads();
#pragma unroll
  for (int i = 0; i < 4; ++i) {     // write transposed
    const int idx = i * 256 + tid;
    const int d = idx >> 3, j = idx & 7;
    WT[d * 128 + e0 + j] = tile[j][d];
  }
  if (sub == 0) {
    const float* av = (tid < 128) ? ((l == 0) ? as0 : (l == 1) ? as1 : as2)
                                  : ((l == 0) ? ad0 : (l == 1) ? ad1 : ad2);
    const int d = tid & 127;
    float acc = 0.f;
#pragma unroll 8
    for (int e = 0; e < 128; ++e) acc += av[e] * W[e * 128 + d];
    ws[OFF_U + l * 256 + tid] = acc;
  }
}

// ---------------------------------------------------------------------------
// Layer 0: one block per (b, patch p, half h). 256 threads, 128 cols, bf16
// LDS staging [128][128]. LDS 38,976 B -> 4 independent blocks/CU (16 waves).
// Output: x~ half-partial (128 floats); feat GEMV deferred to l12.
__global__ __launch_bounds__(256, 4) void l0_kernel(
    const float* __restrict__ x, const int* __restrict__ lengths,
    const float* __restrict__ uvec, float* __restrict__ xt_out) {
  __shared__ unsigned short xs[128 * 128];   // bf16 x[d][n], unpadded
  __shared__ float u_sh[256];
  __shared__ __align__(16) float U4[1024];   // phase A: stp[4][256]
                                             // phase B: am1[0..132) asf[132..264)
                                             //          ap1[264..396) w[396..524)
  __shared__ float htmp[8];
  __shared__ float sF[132], tF[132];         // index k+2, k in [-2..129]

  const int tid  = threadIdx.x;
  const int bid  = blockIdx.x;
  const int b = bid >> 5;
  const int p = (bid >> 1) & 15;
  const int h = bid & 1;
  const int lane = tid & 63;
  const int wave = tid >> 6;
  const int l32  = lane & 31;
  const int hi32 = (lane >> 5) & 1;
  const int c0 = h * 128;

  u_sh[tid] = uvec[tid];

  // halo column load (waves 0,1 -> col cA; waves 2,3 -> col cB), issued early
  const int grp = tid >> 7;
  const int dh  = tid & 127;
  const int hc  = (h ? 126 : 128) + grp;               // absolute col in patch
  const float hv = x[((size_t)b * 128 + dh) * 4096 + p * 256 + hc];
  __syncthreads();   // u_sh ready

  // ---- stage x half-patch into LDS (bf16), fused fp32 s,t partial dots ----
  const float* xb = x + ((size_t)b * 128) * 4096 + p * 256 + c0;
  float s0 = 0.f, s1 = 0.f, s2 = 0.f, s3 = 0.f;
  float t0 = 0.f, t1 = 0.f, t2 = 0.f, t3 = 0.f;
#pragma unroll 8
  for (int it = 0; it < 16; ++it) {
    const int d = it * 8 + wave * 2 + hi32;
    const float4 v = *(const float4*)(xb + (size_t)d * 4096 + l32 * 4);
    const float us = u_sh[d], ud = u_sh[128 + d];
    s0 += v.x * us; s1 += v.y * us; s2 += v.z * us; s3 += v.w * us;
    t0 += v.x * ud; t1 += v.y * ud; t2 += v.z * ud; t3 += v.w * ud;
    ushort4 pk;
    pk.x = f2bf(v.x); pk.y = f2bf(v.y); pk.z = f2bf(v.z); pk.w = f2bf(v.w);
    *(ushort4*)(&xs[d * 128 + l32 * 4]) = pk;
  }

  // ---- halo products, per-wave 64-lane shfl reduce -> htmp ----
  {
    float ps = hv * u_sh[dh];
    float pt = hv * u_sh[128 + dh];
#pragma unroll
    for (int off = 32; off >= 1; off >>= 1) {
      ps += __shfl_xor(ps, off);
      pt += __shfl_xor(pt, off);
    }
    if (lane == 0) { htmp[wave * 2] = ps; htmp[wave * 2 + 1] = pt; }
  }

  // ---- fold hi32 halves of s,t; write per-wave partials to stp ----
  s0 += __shfl_xor(s0, 32); s1 += __shfl_xor(s1, 32);
  s2 += __shfl_xor(s2, 32); s3 += __shfl_xor(s3, 32);
  t0 += __shfl_xor(t0, 32); t1 += __shfl_xor(t1, 32);
  t2 += __shfl_xor(t2, 32); t3 += __shfl_xor(t3, 32);
  if (hi32 == 0) {
    const int n4 = l32 * 4;
    *(float4*)(&U4[wave * 256 + n4])       = make_float4(s0, s1, s2, s3);
    *(float4*)(&U4[wave * 256 + 128 + n4]) = make_float4(t0, t1, t2, t3);
  }
  __syncthreads();

  {   // combine across 4 waves -> sF/tF main range (k=0..127 -> idx 2..129)
    const float r = U4[tid] + U4[256 + tid] + U4[512 + tid] + U4[768 + tid];
    if (tid < 128) sF[tid + 2] = r; else tF[tid - 126] = r;
  }
  if (tid < 4) {   // halo scalars into sF/tF extremes
    // q: 0=s@cA, 1=t@cA, 2=s@cB, 3=t@cB; cA waves {0,1}, cB waves {2,3}
    const int base = (tid >> 1) * 4 + (tid & 1);
    const float v = htmp[base] + htmp[base + 2];
    if (h == 0) {        // cA=col 128 (k=128), cB=col 129 (k=129)
      if (tid == 0) sF[130] = v;
      else if (tid == 1) tF[130] = v;
      else if (tid == 2) sF[131] = v;
    } else {             // cA=col 126 (k=-2), cB=col 127 (k=-1)
      if (tid == 0) sF[0] = v;
      else if (tid == 2) sF[1] = v;
      else if (tid == 3) tF[1] = v;
    }
  }
  __syncthreads();

  const int len = lengths[b];

  if (tid <= 128) {  // attention for dst k in [h?-1:0 .. h?127:128]
    const int k = tid - (h ? 1 : 0);
    const int a = c0 + k;
    const float tj = tF[k + 2];
    const float ls = lrelu(sF[k + 2] + tj);
    const float lm = (a > 0)   ? lrelu(sF[k + 1] + tj) : -1e30f;
    const float lp = (a < 255) ? lrelu(sF[k + 3] + tj) : -1e30f;
    const float mx = fmaxf(ls, fmaxf(lm, lp));
    const float em = (a > 0)   ? __expf(lm - mx) : 0.f;
    const float es = __expf(ls - mx);
    const float ep = (a < 255) ? __expf(lp - mx) : 0.f;
    const float vj = ((p * 256 + a) < len) ? 1.f : 0.f;
    const float sc = vj / (em + es + ep);
    U4[k + 2] = em * sc;          // am1
    U4[132 + k + 2] = es * sc;    // asf
    U4[264 + k + 2] = ep * sc;    // ap1
  }
  __syncthreads();

  if (tid < 128) {   // source weights over this block's 128 cols
    const int n = tid;
    const int a = c0 + n;
    float w = U4[132 + n + 2];
    if (a < 255) w += U4[n + 3];
    if (a > 0)   w += U4[264 + n + 1];
    U4[396 + n] = w;
  }
  __syncthreads();

  {   // x~_half[d] = sum over 128 cols of w[n]*x[d][n]; rotated, ~conflict-free
    const int d = tid >> 1, half = tid & 1;
    float acc = 0.f;
#pragma unroll 8
    for (int j = 0; j < 32; ++j) {
      const int jj = (j + d) & 31;
      const int n  = half * 64 + jj * 2;
      const unsigned pair = *(const unsigned*)(&xs[d * 128 + n]);
      const float f0 = __uint_as_float(pair << 16);
      const float f1 = __uint_as_float(pair & 0xFFFF0000u);
      const float2 w2 = *(const float2*)(&U4[396 + n]);
      acc += w2.x * f0 + w2.y * f1;
    }
    acc += __shfl_xor(acc, 1);
    if (half == 0)
      xt_out[(((size_t)b * 16 + p) * 2 + h) * 128 + d] = acc;
  }
}

// ---------------------------------------------------------------------------
// Fused: feat GEMV (W0) + layer1 + layer2. One block per b, 256 threads.
// [verbatim from round 6]
__global__ __launch_bounds__(256) void l12_kernel(
    const float* __restrict__ xtp, const int* __restrict__ lengths,
    const float* __restrict__ ws,
    const float* __restrict__ b0, const float* __restrict__ b1,
    const float* __restrict__ b2, float* __restrict__ out) {
  __shared__ float xt[16][128];
  __shared__ float pr[2][16][128];
  __shared__ float feat[16][128];
  __shared__ float spt[2][16][16];
  __shared__ float s1[16], t1[16], am[16], asf[16], ap[16], w16[16];
  __shared__ float rc_sh[16];
  __shared__ float x1t[4][128];
  __shared__ float h1[4][128];

  const int tid = threadIdx.x;
  const int b = blockIdx.x;
  const float* WT0 = ws + OFF_WT;
  const float* WT1 = ws + OFF_WT + 16384;
  const float* WT2 = ws + OFF_WT + 32768;
  const float* u1  = ws + OFF_U + 256;
  const int len = lengths[b];

#pragma unroll
  for (int i = 0; i < 8; ++i) {   // combine half-patch partials
    const int pp = i * 2 + (tid >> 7);
    const int d = tid & 127;
    const size_t base = (((size_t)b * 16 + pp) * 2) * 128;
    xt[pp][d] = xtp[base + d] + xtp[base + 128 + d];
  }
  if (tid < 16) {
    const int rem = len - tid * 256;
    const int cnt = rem < 0 ? 0 : (rem > 256 ? 256 : rem);
    rc_sh[tid] = cnt > 0 ? 1.f / (float)cnt : 0.f;
  }
  __syncthreads();

  {   // feat[p][e] = sum_d xt[p][d] * WT0[d*128+e]
    const int e = tid & 127, dhalf = tid >> 7;
    float acc[16];
#pragma unroll
    for (int q = 0; q < 16; ++q) acc[q] = 0.f;
#pragma unroll 4
    for (int k = 0; k < 64; ++k) {
      const int d = dhalf * 64 + k;
      const float wv = WT0[d * 128 + e];
#pragma unroll
      for (int q = 0; q < 16; ++q) acc[q] += xt[q][d] * wv;
    }
#pragma unroll
    for (int q = 0; q < 16; ++q) pr[dhalf][q][e] = acc[q];
  }
  __syncthreads();
  {
    const int e = tid & 127, ph = tid >> 7;
    const float bb = b0[e];
#pragma unroll
    for (int i = 0; i < 8; ++i) {
      const int q = ph * 8 + i;
      const float rcv = rc_sh[q];
      const float f = (pr[0][q][e] + pr[1][q][e]) * rcv + bb;
      feat[q][e] = (rcv == 0.f) ? 0.f : f;
    }
  }
  __syncthreads();

  {   // layer-1 s,t partials
    const int q = tid >> 4, sl = tid & 15;
    float ps = 0.f, pt = 0.f;
#pragma unroll
    for (int k = 0; k < 8; ++k) {
      const int e = sl * 8 + k;
      const float f = feat[q][e];
      ps += f * u1[e];
      pt += f * u1[128 + e];
    }
    spt[0][q][sl] = ps; spt[1][q][sl] = pt;
  }
  __syncthreads();
  if (tid < 32) {
    const int q = tid >> 4, pp = tid & 15;
    float a = 0.f;
#pragma unroll
    for (int i = 0; i < 16; ++i) a += spt[q][pp][i];
    if (q == 0) s1[pp] = a; else t1[pp] = a;
  }
  __syncthreads();
  if (tid < 16) {   // attention within groups of 4
    const int jl = tid & 3;
    const float tj = t1[tid];
    const float ls = lrelu(s1[tid] + tj);
    const float lm = (jl > 0) ? lrelu(s1[tid - 1] + tj) : -1e30f;
    const float lp = (jl < 3) ? lrelu(s1[tid + 1] + tj) : -1e30f;
    const float mx = fmaxf(ls, fmaxf(lm, lp));
    const float em = (jl > 0) ? __expf(lm - mx) : 0.f;
    const float es = __expf(ls - mx);
    const float ep = (jl < 3) ? __expf(lp - mx) : 0.f;
    const float sc = 1.f / (em + es + ep);
    am[tid] = em * sc; asf[tid] = es * sc; ap[tid] = ep * sc;
  }
  __syncthreads();
  if (tid < 16) {
    const int jl = tid & 3;
    float w = asf[tid];
    if (jl < 3) w += am[tid + 1];
    if (jl > 0) w += ap[tid - 1];
    w16[tid] = w;
  }
  __syncthreads();
#pragma unroll
  for (int r = 0; r < 2; ++r) {   // x1t[g][d] = sum_j w*feat
    const int idx = r * 256 + tid;
    const int g = idx >> 7, d = idx & 127;
    x1t[g][d] = w16[g * 4] * feat[g * 4][d] + w16[g * 4 + 1] * feat[g * 4 + 1][d]
              + w16[g * 4 + 2] * feat[g * 4 + 2][d] + w16[g * 4 + 3] * feat[g * 4 + 3][d];
  }
  __syncthreads();
  {   // layer-1 GEMV
    const int e = tid & 127, gh = tid >> 7;
    float a0 = 0.f, a1 = 0.f;
#pragma unroll 8
    for (int d = 0; d < 128; ++d) {
      const float wv = WT1[d * 128 + e];
      a0 += x1t[gh * 2][d] * wv;
      a1 += x1t[gh * 2 + 1][d] * wv;
    }
    h1[gh * 2][e]     = a0 * 0.25f + b1[e];
    h1[gh * 2 + 1][e] = a1 * 0.25f + b1[e];
  }
  __syncthreads();
  {   // layer-2 GEMV + output
    const int e = tid & 127, gh = tid >> 7;
    float a0 = 0.f, a1 = 0.f;
#pragma unroll 8
    for (int d = 0; d < 128; ++d) {
      const float wv = WT2[d * 128 + e];
      a0 += h1[gh * 2][d] * wv;
      a1 += h1[gh * 2 + 1][d] * wv;
    }
    const float bb = b2[e];
    out[((size_t)b * 128 + e) * 4 + gh * 2]     = a0 + bb;
    out[((size_t)b * 128 + e) * 4 + gh * 2 + 1] = a1 + bb;
  }
}

// ---------------------------------------------------------------------------
extern "C" void kernel_launch(void* const* d_in, const int* in_sizes, int n_in,
                              void* d_out, int out_size, void* d_ws, size_t ws_size,
                              hipStream_t stream) {
  (void)in_sizes; (void)n_in; (void)out_size; (void)ws_size;
  const float* x       = (const float*)d_in[0];
  const int*   lengths = (const int*)  d_in[1];
  const float* W0  = (const float*)d_in[2];
  const float* as0 = (const float*)d_in[3];
  const float* ad0 = (const float*)d_in[4];
  const float* b0  = (const float*)d_in[5];
  const float* W1  = (const float*)d_in[6];
  const float* as1 = (const float*)d_in[7];
  const float* ad1 = (const float*)d_in[8];
  const float* b1  = (const float*)d_in[9];
  const float* W2  = (const float*)d_in[10];
  const float* as2 = (const float*)d_in[11];
  const float* ad2 = (const float*)d_in[12];
  const float* b2  = (const float*)d_in[13];
  float* ws  = (float*)d_ws;
  float* out = (float*)d_out;

  setup_kernel<<<48, 256, 0, stream>>>(W0, as0, ad0, W1, as1, ad1, W2, as2, ad2, ws);
  l0_kernel<<<2048, 256, 0, stream>>>(x, lengths, ws + OFF_U, ws + OFF_XT);
  l12_kernel<<<64, 256, 0, stream>>>(ws + OFF_XT, lengths, ws, b0, b1, b2, out);
}